// Round 18
// baseline (23235.199 us; speedup 1.0000x reference)
//
#include <hip/hip_runtime.h>
#include <hip/hip_fp16.h>
#include <math.h>

#define Bz 16
#define Tz 1024
#define Ez 768
#define E3 2304
#define Vz 50257
#define NBK 256          // 256 blocks: 128 layer-0, 128 layer-1, 6 columns each
#define LN_EPS 1e-5f
#define VEC (Bz*Ez)      // 12288 floats per h vector
#define VECW 6144        // packed fp16: u32 words per h vector
#define EP 772           // fp32 LDS row stride (lm_head only)
#define EPW 392          // packed u32 LDS row stride (384 + 8 pad, 16B-mult)
#define WROWW 384        // u32 words per weight row (768 fp16)

__device__ __forceinline__ float dot4acc(float acc, float4 w, float4 h){
  acc = fmaf(w.x,h.x,acc); acc = fmaf(w.y,h.y,acc);
  acc = fmaf(w.z,h.z,acc); acc = fmaf(w.w,h.w,acc);
  return acc;
}
__device__ __forceinline__ float sigm(float x){ return 1.0f/(1.0f+expf(-x)); }

__device__ __forceinline__ unsigned pack2(float a, float b){
  __half2 h = __floats2half2_rn(a, b);
  union{__half2 h2; unsigned u;} cv; cv.h2 = h; return cv.u;
}
__device__ __forceinline__ float2 unpack2(unsigned u){
  union{unsigned u; __half2 h2;} cv; cv.u = u;
  return __half22float2(cv.h2);
}
__device__ __forceinline__ float4 up4(uint2 u){
  const float2 a = unpack2(u.x), b = unpack2(u.y);
  return make_float4(a.x, a.y, b.x, b.y);
}

// ---- Staging envelope (empirical, R4-R13): UC h-exchange = scalar 32-bit
// relaxed-atomic loads feeding IMMEDIATE LDS stores, <=4 outstanding.
// Now raw u32 copies (packed fp16), even closer to the original pattern. ----

__device__ __forceinline__ void stage_one_w(const unsigned* __restrict__ src,
                                            unsigned (*dst)[EPW], int tid){
#pragma unroll
  for (int k=0;k<3;k++){
    const int u0 = tid + (k<<9);
    const int u1 = u0 + 1536;
    const int u2 = u0 + 3072;
    const int u3 = u0 + 4608;
    const unsigned a0 = __hip_atomic_load(src+u0, __ATOMIC_RELAXED, __HIP_MEMORY_SCOPE_AGENT);
    const unsigned a1 = __hip_atomic_load(src+u1, __ATOMIC_RELAXED, __HIP_MEMORY_SCOPE_AGENT);
    const unsigned a2 = __hip_atomic_load(src+u2, __ATOMIC_RELAXED, __HIP_MEMORY_SCOPE_AGENT);
    const unsigned a3 = __hip_atomic_load(src+u3, __ATOMIC_RELAXED, __HIP_MEMORY_SCOPE_AGENT);
    {const int b=u0/384, c=u0-b*384; dst[b][c]=a0;}
    {const int b=u1/384, c=u1-b*384; dst[b][c]=a1;}
    {const int b=u2/384, c=u2-b*384; dst[b][c]=a2;}
    {const int b=u3/384, c=u3-b*384; dst[b][c]=a3;}
  }
}

__device__ __forceinline__ void stage_two_w(const unsigned* __restrict__ srcX,
                                            unsigned (*dstX)[EPW],
                                            const unsigned* __restrict__ srcH,
                                            unsigned (*dstH)[EPW], int tid){
#pragma unroll
  for (int k=0;k<6;k++){
    const int u0 = tid + (k<<9);
    const int u1 = u0 + 3072;
    const unsigned x0 = __hip_atomic_load(srcX+u0, __ATOMIC_RELAXED, __HIP_MEMORY_SCOPE_AGENT);
    const unsigned x1 = __hip_atomic_load(srcX+u1, __ATOMIC_RELAXED, __HIP_MEMORY_SCOPE_AGENT);
    const unsigned h0 = __hip_atomic_load(srcH+u0, __ATOMIC_RELAXED, __HIP_MEMORY_SCOPE_AGENT);
    const unsigned h1 = __hip_atomic_load(srcH+u1, __ATOMIC_RELAXED, __HIP_MEMORY_SCOPE_AGENT);
    const int b0=u0/384, c0_=u0-b0*384;
    const int b1=u1/384, c1_=u1-b1*384;
    dstX[b0][c0_]=x0;  dstX[b1][c1_]=x1;
    dstH[b0][c0_]=h0;  dstH[b1][c1_]=h1;
  }
}

__device__ __forceinline__ void zero_w(unsigned (*dst)[EPW], int tid){
#pragma unroll
  for (int k=0;k<12;k++){
    const int u = tid + (k<<9);
    const int b = u/384, c = u - b*384;
    dst[b][c] = 0u;
  }
}

// ---------------------------------------------------------------------------
// Pre-kernel: convert Wih/Whh (both layers) to packed fp16.
// Row order: [(L,mat) blocks of 2304 rows], mat 0=ih 1=hh; 384 u32/row.
// ---------------------------------------------------------------------------
__global__ __launch_bounds__(256) void conv_w16(
    const float* __restrict__ Wih, const float* __restrict__ Whh,
    unsigned* __restrict__ w16)
{
  const size_t total = (size_t)4*E3*WROWW;
  const size_t gid = (size_t)blockIdx.x*256 + threadIdx.x;
  for (size_t u = gid; u < total; u += (size_t)1024*256){
    const int gr = (int)(u/WROWW), w = (int)(u - (size_t)gr*WROWW);
    const int L = gr/(2*E3), rem = gr - L*2*E3;
    const int mat = rem/E3, row = rem - mat*E3;
    const float* src = (mat ? Whh : Wih) + (size_t)L*E3*Ez + (size_t)row*Ez + (w<<1);
    w16[u] = pack2(src[0], src[1]);
  }
}

// ---------------------------------------------------------------------------
// Persistent cooperative scan; layer-skewed; R15 structure (256 blocks,
// 6 cols/block, fp16 h-exchange, private fp32 hprev, R14 barrier).
// THIS ROUND: weights in packed fp16 (L2-resident: 1.77 MB/XCD vs 3.54 fp32
// that thrashed 4MiB L2 -> ~4.2 MB/step HBM refetch, the non-UC half of
// FETCH). LDS operands also packed fp16 (h already fp16-rounded: lossless).
// ---------------------------------------------------------------------------
__global__ __launch_bounds__(512) void gru_scan(
    const int* __restrict__ idx, const float* __restrict__ wte,
    const unsigned* __restrict__ w16,
    const float* __restrict__ bih, const float* __restrict__ bhh,
    unsigned* __restrict__ h0g, unsigned* __restrict__ h1g,
    float* __restrict__ h1f,
    unsigned* __restrict__ flags, unsigned* __restrict__ go)
{
  __shared__ unsigned bufX0[Bz][EPW];  // L0: x(t) ping   | L1: h0(t)
  __shared__ unsigned bufX1[Bz][EPW];  // L0: x(t) pong   | L1: unused
  __shared__ unsigned bufH [Bz][EPW];  // h_prev (own layer)
  __shared__ float gates[36][17];
  __shared__ float biasS[36];
  __shared__ float hprev[Bz][6];       // own columns' h, exact fp32

  const int tid = threadIdx.x, bx = blockIdx.x;
  const int L = bx>>7, sub = bx&127, c0 = sub*6;
  const int wv = tid>>6, lane = tid&63, kq = lane&15, bb = lane>>4;

  // 9 weight-row pointers per wave (tid<256). m = (wv&3)*9+r in [0,36):
  const unsigned* wrow[9];
#pragma unroll
  for (int r=0;r<9;r++){
    const int m = (wv&3)*9+r, mat = m/18, mm = m%18, g = mm/6, cc = mm-g*6;
    const int grow = g*Ez + c0 + cc;
    wrow[r] = w16 + (size_t)((L*2+mat)*E3 + grow)*WROWW;
  }
  if (tid<36){
    const int mat = tid/18, mm = tid%18, g = mm/6, cc = mm-g*6;
    biasS[tid] = (mat ? bhh : bih)[L*E3 + g*Ez + c0 + cc];
  }
  if (tid<96) hprev[tid&15][tid>>4] = 0.f;

  // preload x(0) for layer 0 (cached wte gather -> packed LDS)
  if (L==0){
#pragma unroll
    for (int k=0;k<12;k++){
      const int w = tid + (k<<9);
      const int b = w/384, c = w - b*384;
      const int row = idx[b*Tz];
      const float2 v = *(const float2*)(wte + (size_t)row*Ez + (c<<1));
      bufX0[b][c] = pack2(v.x, v.y);
    }
  }
  __syncthreads();

  for (int s=0; s<=Tz; ++s){
    // ---- grid wait (R14 barrier) ----
    if (s>0){
      const unsigned tgt = (unsigned)s;
      if (bx==0){
        if (tid<64){
          const unsigned* f = flags + (tid<<2);
          for(;;){
            const unsigned a0 = __hip_atomic_load(f+0, __ATOMIC_RELAXED, __HIP_MEMORY_SCOPE_AGENT);
            const unsigned a1 = __hip_atomic_load(f+1, __ATOMIC_RELAXED, __HIP_MEMORY_SCOPE_AGENT);
            const unsigned a2 = __hip_atomic_load(f+2, __ATOMIC_RELAXED, __HIP_MEMORY_SCOPE_AGENT);
            const unsigned a3 = __hip_atomic_load(f+3, __ATOMIC_RELAXED, __HIP_MEMORY_SCOPE_AGENT);
            const int ok = (a0>=tgt) & (a1>=tgt) & (a2>=tgt) & (a3>=tgt);
            if (__all(ok)) break;
            __builtin_amdgcn_s_sleep(1);
          }
          __hip_atomic_store(go + (tid<<5), tgt,
                             __ATOMIC_RELAXED, __HIP_MEMORY_SCOPE_AGENT);
        }
      } else {
        if (tid==0){
          const unsigned* gp = go + ((bx&63)<<5);
          while (__hip_atomic_load(gp, __ATOMIC_RELAXED, __HIP_MEMORY_SCOPE_AGENT) < tgt)
            __builtin_amdgcn_s_sleep(2);
        }
      }
      __syncthreads();
    }

    const bool active = (L==0) ? (s<Tz) : (s>0);
    if (active){
      const int t = (L==0) ? s : s-1;

      // ---- stage phase (packed u32 UC -> packed LDS) ----
      if (L==0){
        if (t==0) zero_w(bufH, tid);
        else      stage_one_w(h0g + (size_t)((s-1)&1)*VECW, bufH, tid);
      } else {
        if (t==0){
          stage_one_w(h0g + (size_t)((s-1)&1)*VECW, bufX0, tid);
          zero_w(bufH, tid);
        } else {
          stage_two_w(h0g + (size_t)((s-1)&1)*VECW, bufX0,
                      h1g + (size_t)(s&1)*VECW,     bufH, tid);
        }
      }
      __syncthreads();

      // ---- matmul on waves 0-3: fp16 weights x fp16 operands, fp32 acc ----
      if (tid < 256){
        const unsigned (*V)[EPW];
        if (wv<2) V = (L==0) ? ((s&1) ? bufX1 : bufX0) : bufX0;
        else      V = bufH;

        float acc[9][4];
#pragma unroll
        for (int r=0;r<9;r++)
#pragma unroll
          for (int bi=0;bi<4;bi++) acc[r][bi]=0.f;

#pragma unroll 4
        for (int j=0;j<12;j++){
          const int kk = (j<<5) + (kq<<1);     // u32 word index, 0..383
          float4 wf[9];
#pragma unroll
          for (int r=0;r<9;r++) wf[r] = up4(*(const uint2*)(wrow[r] + kk));
#pragma unroll
          for (int bi=0;bi<4;bi++){
            const float4 hv = up4(*(const uint2*)&V[bb*4+bi][kk]);
#pragma unroll
            for (int r=0;r<9;r++) acc[r][bi] = dot4acc(acc[r][bi], wf[r], hv);
          }
        }
#pragma unroll
        for (int r=0;r<9;r++)
#pragma unroll
          for (int bi=0;bi<4;bi++){
            float a = acc[r][bi];
            a += __shfl_xor(a,1); a += __shfl_xor(a,2);
            a += __shfl_xor(a,4); a += __shfl_xor(a,8);
            acc[r][bi]=a;
          }
        if (kq==0){
#pragma unroll
          for (int r=0;r<9;r++)
#pragma unroll
            for (int bi=0;bi<4;bi++) gates[(wv&3)*9+r][bb*4+bi] = acc[r][bi];
        }
      }
      __syncthreads();

      // ---- nonlinearity + publish (48 threads: 16 b x 3 col-pairs) ----
      if (tid < 48){
        const int b = tid&15, j = tid>>4;      // pair j: cols 2j, 2j+1
        float hv2[2];
#pragma unroll
        for (int e=0;e<2;e++){
          const int cc = 2*j+e;
          const float gir = gates[cc   ][b] + biasS[cc];
          const float giz = gates[6+cc ][b] + biasS[6+cc];
          const float gin = gates[12+cc][b] + biasS[12+cc];
          const float ghr = gates[18+cc][b] + biasS[18+cc];
          const float ghz = gates[24+cc][b] + biasS[24+cc];
          const float ghn = gates[30+cc][b] + biasS[30+cc];
          const float r = sigm(gir+ghr);
          const float z = sigm(giz+ghz);
          const float n = tanhf(fmaf(r, ghn, gin));
          const float hp = hprev[b][cc];       // exact fp32 private state
          hv2[e] = fmaf(z, hp - n, n);
          hprev[b][cc] = hv2[e];
        }
        unsigned* hOutW = (L==0) ? (h0g + (size_t)(s&1)*VECW)
                                 : (h1g + (size_t)((s-1)&1)*VECW);
        const unsigned pk = pack2(hv2[0], hv2[1]);
        __hip_atomic_store(hOutW + b*384 + sub*3 + j, pk,
                           __ATOMIC_RELAXED, __HIP_MEMORY_SCOPE_AGENT);
        if (L==1 && t==Tz-1){                  // final h1 in fp32 for LN
          h1f[b*Ez + c0 + 2*j    ] = hv2[0];
          h1f[b*Ez + c0 + 2*j + 1] = hv2[1];
        }
      }
    }

    // ---- arrive: syncthreads drains vmcnt, then flag ----
    __syncthreads();
    if (tid==0)
      __hip_atomic_store(flags + bx, (unsigned)(s+1),
                         __ATOMIC_RELAXED, __HIP_MEMORY_SCOPE_AGENT);

    // ---- prefetch x(s+1) AFTER arrive (cached wte gather) ----
    if (L==0 && active && s+1 < Tz){
      unsigned (*bx_)[EPW] = ((s+1)&1) ? bufX1 : bufX0;
#pragma unroll
      for (int k=0;k<12;k++){
        const int w = tid + (k<<9);
        const int b = w/384, c = w - b*384;
        const int row = idx[b*Tz + (s+1)];
        const float2 v = *(const float2*)(wte + (size_t)row*Ez + (c<<1));
        bx_[b][c] = pack2(v.x, v.y);
      }
    }
  }
}

// LayerNorm of final h1 (fp32) -> ln
__global__ __launch_bounds__(256) void finalize_ln(
    const float* __restrict__ h1, const float* __restrict__ g,
    float* __restrict__ ln)
{
  const int tid=threadIdx.x, wv=tid>>6, lane=tid&63;
  for (int b=wv; b<Bz; b+=4){
    float sum=0.f;
    for (int c=lane;c<Ez;c+=64) sum += h1[b*Ez+c];
#pragma unroll
    for (int off=32; off; off>>=1) sum += __shfl_xor(sum, off);
    const float mu = sum/(float)Ez;
    float s2=0.f;
    for (int c=lane;c<Ez;c+=64){ const float d=h1[b*Ez+c]-mu; s2=fmaf(d,d,s2); }
#pragma unroll
    for (int off=32; off; off>>=1) s2 += __shfl_xor(s2, off);
    const float inv = rsqrtf(s2/(float)Ez + LN_EPS);
    for (int c=lane;c<Ez;c+=64) ln[b*Ez+c] = (h1[b*Ez+c]-mu)*inv*g[c];
  }
}

// logits[b,v] = dot(ln[b,:], wte[v,:]) ; 64 rows per block, 16 rows per wave.
__global__ __launch_bounds__(256) void lm_head(
    const float* __restrict__ ln, const float* __restrict__ wte,
    float* __restrict__ out)
{
  __shared__ float sLn[Bz][EP];
  const int tid=threadIdx.x;
  for (int i4=tid; i4<Bz*Ez/4; i4+=256){
    const int b = i4/(Ez/4), c = (i4 - b*(Ez/4))<<2;
    *(float4*)(&sLn[b][c]) = *(const float4*)(ln + b*Ez + c);
  }
  __syncthreads();
  const int wv=tid>>6, lane=tid&63, rr=lane>>4, cl=lane&15;
  const int vbase = blockIdx.x*64 + wv*16 + rr;
  float acc[4][16];
#pragma unroll
  for (int k=0;k<4;k++)
#pragma unroll
    for (int b=0;b<16;b++) acc[k][b]=0.f;

  for (int j=0;j<12;j++){
    const int c = (cl<<2) + (j<<6);
    float4 w4[4];
#pragma unroll
    for (int k=0;k<4;k++){
      const int v = vbase + 4*k;
      if (v < Vz) w4[k] = *(const float4*)(wte + (size_t)v*Ez + c);
      else { w4[k].x=w4[k].y=w4[k].z=w4[k].w=0.f; }
    }
#pragma unroll
    for (int b=0;b<16;b++){
      const float4 hv = *(const float4*)(&sLn[b][c]);
#pragma unroll
      for (int k=0;k<4;k++) acc[k][b] = dot4acc(acc[k][b], w4[k], hv);
    }
  }
#pragma unroll
  for (int off=1; off<16; off<<=1)
#pragma unroll
    for (int k=0;k<4;k++)
#pragma unroll
      for (int b=0;b<16;b++) acc[k][b] += __shfl_xor(acc[k][b], off);

  if (cl==0){
#pragma unroll
    for (int k=0;k<4;k++){
      const int v = vbase + 4*k;
      if (v < Vz){
#pragma unroll
        for (int b=0;b<16;b++) out[(size_t)b*Vz + v] = acc[k][b];
      }
    }
  }
}

extern "C" void kernel_launch(void* const* d_in, const int* in_sizes, int n_in,
                              void* d_out, int out_size, void* d_ws, size_t ws_size,
                              hipStream_t stream) {
  const int*   idx = (const int*)  d_in[0];
  const float* wte = (const float*)d_in[1];
  const float* Wih = (const float*)d_in[2];
  const float* bih = (const float*)d_in[3];
  const float* Whh = (const float*)d_in[4];
  const float* bhh = (const float*)d_in[5];
  const float* g   = (const float*)d_in[6];
  float* out = (float*)d_out;

  unsigned* flags = (unsigned*)d_ws;            // words [0,256)
  unsigned* go    = (unsigned*)d_ws + 512;      // words [512,2560): 64 lines
  unsigned* h0g   = (unsigned*)d_ws + 4096;     // 2 x 6144 words (fp16 pairs)
  unsigned* h1g   = h0g + 2*VECW;               // 2 x 6144 words
  float*    h1f   = (float*)(h1g + 2*VECW);     // B*E fp32 final h1
  float*    ln    = h1f + VEC;                  // B*E fp32
  unsigned* w16   = (unsigned*)d_ws + 53248;    // 4*2304*384 words (13.5 MB)

  (void)hipMemsetAsync(d_ws, 0, 16384, stream); // reset flags + go lines

  conv_w16<<<1024, 256, 0, stream>>>(Wih, Whh, w16);

  void* args[] = {(void*)&idx,(void*)&wte,(void*)&w16,(void*)&bih,(void*)&bhh,
                  (void*)&h0g,(void*)&h1g,(void*)&h1f,(void*)&flags,(void*)&go};
  (void)hipLaunchCooperativeKernel((void*)gru_scan, dim3(NBK), dim3(512), args, 0, stream);

  finalize_ln<<<1, 256, 0, stream>>>(h1f, g, ln);
  lm_head<<<786, 256, 0, stream>>>(ln, wte, out);
}

// Round 19
// 20472.134 us; speedup vs baseline: 1.1350x; 1.1350x over previous
//
#include <hip/hip_runtime.h>
#include <hip/hip_fp16.h>
#include <math.h>

#define Bz 16
#define Tz 1024
#define Ez 768
#define E3 2304
#define Vz 50257
#define NBK 256          // 256 blocks: 128 layer-0, 128 layer-1, 6 columns each
#define LN_EPS 1e-5f
#define VEC (Bz*Ez)      // 12288 floats per h vector
#define VECW 6144        // packed fp16: u32 words per h vector
#define EP 772           // padded LDS row stride

__device__ __forceinline__ float dot4acc(float acc, float4 w, float4 h){
  acc = fmaf(w.x,h.x,acc); acc = fmaf(w.y,h.y,acc);
  acc = fmaf(w.z,h.z,acc); acc = fmaf(w.w,h.w,acc);
  return acc;
}
__device__ __forceinline__ float sigm(float x){ return 1.0f/(1.0f+expf(-x)); }

__device__ __forceinline__ unsigned pack2(float a, float b){
  __half2 h = __floats2half2_rn(a, b);
  union{__half2 h2; unsigned u;} cv; cv.h2 = h; return cv.u;
}
__device__ __forceinline__ float2 unpack2(unsigned u){
  union{unsigned u; __half2 h2;} cv; cv.u = u;
  return __half22float2(cv.h2);
}

// ---- Staging envelope (empirical): scalar 32-bit relaxed-atomic loads with
// immediate LDS stores, <=4 outstanding per body. Batched(>=8)/asm/DMA all
// fail. fp16 packing: 1 u32 = 2 h values. Identical to passing R15. ----

__device__ __forceinline__ void stage_one_h(const unsigned* __restrict__ src,
                                            float (*dst)[EP], int tid){
#pragma unroll
  for (int k=0;k<3;k++){
    const int u0 = tid + (k<<9);
    const int u1 = u0 + 1536;
    const int u2 = u0 + 3072;
    const int u3 = u0 + 4608;
    const unsigned a0 = __hip_atomic_load(src+u0, __ATOMIC_RELAXED, __HIP_MEMORY_SCOPE_AGENT);
    const unsigned a1 = __hip_atomic_load(src+u1, __ATOMIC_RELAXED, __HIP_MEMORY_SCOPE_AGENT);
    const unsigned a2 = __hip_atomic_load(src+u2, __ATOMIC_RELAXED, __HIP_MEMORY_SCOPE_AGENT);
    const unsigned a3 = __hip_atomic_load(src+u3, __ATOMIC_RELAXED, __HIP_MEMORY_SCOPE_AGENT);
    {const int b=u0/384, c=(u0-b*384)<<1; const float2 f=unpack2(a0); dst[b][c]=f.x; dst[b][c+1]=f.y;}
    {const int b=u1/384, c=(u1-b*384)<<1; const float2 f=unpack2(a1); dst[b][c]=f.x; dst[b][c+1]=f.y;}
    {const int b=u2/384, c=(u2-b*384)<<1; const float2 f=unpack2(a2); dst[b][c]=f.x; dst[b][c+1]=f.y;}
    {const int b=u3/384, c=(u3-b*384)<<1; const float2 f=unpack2(a3); dst[b][c]=f.x; dst[b][c+1]=f.y;}
  }
}

__device__ __forceinline__ void stage_two_h(const unsigned* __restrict__ srcX,
                                            float (*dstX)[EP],
                                            const unsigned* __restrict__ srcH,
                                            float (*dstH)[EP], int tid){
#pragma unroll
  for (int k=0;k<6;k++){
    const int u0 = tid + (k<<9);
    const int u1 = u0 + 3072;
    const unsigned x0 = __hip_atomic_load(srcX+u0, __ATOMIC_RELAXED, __HIP_MEMORY_SCOPE_AGENT);
    const unsigned x1 = __hip_atomic_load(srcX+u1, __ATOMIC_RELAXED, __HIP_MEMORY_SCOPE_AGENT);
    const unsigned h0 = __hip_atomic_load(srcH+u0, __ATOMIC_RELAXED, __HIP_MEMORY_SCOPE_AGENT);
    const unsigned h1 = __hip_atomic_load(srcH+u1, __ATOMIC_RELAXED, __HIP_MEMORY_SCOPE_AGENT);
    const int b0=u0/384, c0_=(u0-b0*384)<<1;
    const int b1=u1/384, c1_=(u1-b1*384)<<1;
    {const float2 f=unpack2(x0); dstX[b0][c0_]=f.x; dstX[b0][c0_+1]=f.y;}
    {const float2 f=unpack2(x1); dstX[b1][c1_]=f.x; dstX[b1][c1_+1]=f.y;}
    {const float2 f=unpack2(h0); dstH[b0][c0_]=f.x; dstH[b0][c0_+1]=f.y;}
    {const float2 f=unpack2(h1); dstH[b1][c1_]=f.x; dstH[b1][c1_+1]=f.y;}
  }
}

__device__ __forceinline__ void zero_buf(float (*dst)[EP], int tid){
#pragma unroll
  for (int k=0;k<24;k++){
    const int u = tid + (k<<9);
    const int b = u/768, c = u - b*768;
    dst[b][c] = 0.f;
  }
}

// ---------------------------------------------------------------------------
// Persistent cooperative scan; layer-skewed; R15 structure (256 blocks,
// 6 cols/block, fp16 h-exchange, private fp32 hprev, fp32 weights).
// THIS ROUND: DIRECT store-only flag barrier -- every block's wave 0 polls
// all 256 flags itself (64 lanes x 4 loads + __all). Removes the two-level
// barrier's aggregate+go relay (2 serial L3 hops/step). The poll pattern is
// the exact one block 0 has run successfully since R7.
// ---------------------------------------------------------------------------
__global__ __launch_bounds__(512) void gru_scan(
    const int* __restrict__ idx, const float* __restrict__ wte,
    const float* __restrict__ Wih, const float* __restrict__ bih,
    const float* __restrict__ Whh, const float* __restrict__ bhh,
    unsigned* __restrict__ h0g, unsigned* __restrict__ h1g,
    float* __restrict__ h1f,
    unsigned* __restrict__ flags)
{
  __shared__ float bufX0[Bz][EP];   // L0: x(t) ping   | L1: h0(t)
  __shared__ float bufX1[Bz][EP];   // L0: x(t) pong   | L1: unused
  __shared__ float bufH [Bz][EP];   // h_prev (own layer, fp16-rounded)
  __shared__ float gates[36][17];   // [row m][batch]
  __shared__ float biasS[36];
  __shared__ float hprev[Bz][6];    // own columns' h, exact fp32, persists

  const int tid = threadIdx.x, bx = blockIdx.x;
  const int L = bx>>7, sub = bx&127, c0 = sub*6;
  const int wv = tid>>6, lane = tid&63, kq = lane&15, bb = lane>>4;

  const float* WihL = Wih + (size_t)L*E3*Ez;
  const float* WhhL = Whh + (size_t)L*E3*Ez;

  const float* wrow[9];
#pragma unroll
  for (int r=0;r<9;r++){
    const int m = (wv&3)*9+r, mat = m/18, mm = m%18, g = mm/6, cc = mm-g*6;
    wrow[r] = (mat ? WhhL : WihL) + (size_t)(g*Ez + c0 + cc)*Ez;
  }
  if (tid<36){
    const int mat = tid/18, mm = tid%18, g = mm/6, cc = mm-g*6;
    biasS[tid] = (mat ? bhh : bih)[L*E3 + g*Ez + c0 + cc];
  }
  if (tid<96) hprev[tid&15][tid>>4] = 0.f;

  // preload x(0) for layer 0 (512 threads x 6 float4)
  if (L==0){
#pragma unroll
    for (int k4=0;k4<6;k4++){
      const int i4 = tid + (k4<<9);
      const int b = i4/192, c4 = i4 - b*192;
      const int row = idx[b*Tz];
      *(float4*)&bufX0[b][c4<<2] = *(const float4*)(wte + (size_t)row*Ez + (c4<<2));
    }
  }
  __syncthreads();

  for (int s=0; s<=Tz; ++s){
    // ---- grid wait: DIRECT poll of all 256 flags by wave 0 ----
    if (s>0){
      const unsigned tgt = (unsigned)s;
      if (tid<64){
        const unsigned* f = flags + (tid<<2);
        for(;;){
          const unsigned a0 = __hip_atomic_load(f+0, __ATOMIC_RELAXED, __HIP_MEMORY_SCOPE_AGENT);
          const unsigned a1 = __hip_atomic_load(f+1, __ATOMIC_RELAXED, __HIP_MEMORY_SCOPE_AGENT);
          const unsigned a2 = __hip_atomic_load(f+2, __ATOMIC_RELAXED, __HIP_MEMORY_SCOPE_AGENT);
          const unsigned a3 = __hip_atomic_load(f+3, __ATOMIC_RELAXED, __HIP_MEMORY_SCOPE_AGENT);
          const int ok = (a0>=tgt) & (a1>=tgt) & (a2>=tgt) & (a3>=tgt);
          if (__all(ok)) break;
          __builtin_amdgcn_s_sleep(1);
        }
      }
      __syncthreads();
    }

    const bool active = (L==0) ? (s<Tz) : (s>0);
    if (active){
      const int t = (L==0) ? s : s-1;

      // ---- stage phase (packed fp16 UC -> fp32 LDS) ----
      if (L==0){
        if (t==0) zero_buf(bufH, tid);
        else      stage_one_h(h0g + (size_t)((s-1)&1)*VECW, bufH, tid);
      } else {
        if (t==0){
          stage_one_h(h0g + (size_t)((s-1)&1)*VECW, bufX0, tid);
          zero_buf(bufH, tid);
        } else {
          stage_two_h(h0g + (size_t)((s-1)&1)*VECW, bufX0,
                      h1g + (size_t)(s&1)*VECW,     bufH, tid);
        }
      }
      __syncthreads();

      // ---- matmul on waves 0-3 only ----
      if (tid < 256){
        const float (*V)[EP];
        if (wv<2) V = (L==0) ? ((s&1) ? bufX1 : bufX0) : bufX0;
        else      V = bufH;

        float acc[9][4];
#pragma unroll
        for (int r=0;r<9;r++)
#pragma unroll
          for (int bi=0;bi<4;bi++) acc[r][bi]=0.f;

#pragma unroll 4
        for (int j=0;j<12;j++){
          const int kk = (j<<6) + (kq<<2);
          float4 wv4[9];
#pragma unroll
          for (int r=0;r<9;r++) wv4[r] = *(const float4*)(wrow[r] + kk);
#pragma unroll
          for (int bi=0;bi<4;bi++){
            const float4 hv = *(const float4*)&V[bb*4+bi][kk];
#pragma unroll
            for (int r=0;r<9;r++) acc[r][bi] = dot4acc(acc[r][bi], wv4[r], hv);
          }
        }
#pragma unroll
        for (int r=0;r<9;r++)
#pragma unroll
          for (int bi=0;bi<4;bi++){
            float a = acc[r][bi];
            a += __shfl_xor(a,1); a += __shfl_xor(a,2);
            a += __shfl_xor(a,4); a += __shfl_xor(a,8);
            acc[r][bi]=a;
          }
        if (kq==0){
#pragma unroll
          for (int r=0;r<9;r++)
#pragma unroll
            for (int bi=0;bi<4;bi++) gates[(wv&3)*9+r][bb*4+bi] = acc[r][bi];
        }
      }
      __syncthreads();

      // ---- nonlinearity + publish (48 threads: 16 b x 3 col-pairs) ----
      if (tid < 48){
        const int b = tid&15, j = tid>>4;      // pair j: cols 2j, 2j+1
        float hv2[2];
#pragma unroll
        for (int e=0;e<2;e++){
          const int cc = 2*j+e;
          const float gir = gates[cc   ][b] + biasS[cc];
          const float giz = gates[6+cc ][b] + biasS[6+cc];
          const float gin = gates[12+cc][b] + biasS[12+cc];
          const float ghr = gates[18+cc][b] + biasS[18+cc];
          const float ghz = gates[24+cc][b] + biasS[24+cc];
          const float ghn = gates[30+cc][b] + biasS[30+cc];
          const float r = sigm(gir+ghr);
          const float z = sigm(giz+ghz);
          const float n = tanhf(fmaf(r, ghn, gin));
          const float hp = hprev[b][cc];       // exact fp32 private state
          hv2[e] = fmaf(z, hp - n, n);
          hprev[b][cc] = hv2[e];
        }
        unsigned* hOutW = (L==0) ? (h0g + (size_t)(s&1)*VECW)
                                 : (h1g + (size_t)((s-1)&1)*VECW);
        const unsigned pk = pack2(hv2[0], hv2[1]);
        __hip_atomic_store(hOutW + b*384 + sub*3 + j, pk,
                           __ATOMIC_RELAXED, __HIP_MEMORY_SCOPE_AGENT);
        if (L==1 && t==Tz-1){                  // final h1 in fp32 for LN
          h1f[b*Ez + c0 + 2*j    ] = hv2[0];
          h1f[b*Ez + c0 + 2*j + 1] = hv2[1];
        }
      }
    }

    // ---- arrive: syncthreads drains vmcnt, then flag (store-only) ----
    __syncthreads();
    if (tid==0)
      __hip_atomic_store(flags + bx, (unsigned)(s+1),
                         __ATOMIC_RELAXED, __HIP_MEMORY_SCOPE_AGENT);

    // ---- prefetch x(s+1) AFTER arrive (off the barrier critical path) ----
    if (L==0 && active && s+1 < Tz){
      float (*bx_)[EP] = ((s+1)&1) ? bufX1 : bufX0;
#pragma unroll
      for (int k4=0;k4<6;k4++){
        const int i4 = tid + (k4<<9);
        const int b = i4/192, c4 = i4 - b*192;
        const int row = idx[b*Tz + (s+1)];
        *(float4*)&bx_[b][c4<<2] = *(const float4*)(wte + (size_t)row*Ez + (c4<<2));
      }
    }
  }
}

// LayerNorm of final h1 (fp32) -> ln
__global__ __launch_bounds__(256) void finalize_ln(
    const float* __restrict__ h1, const float* __restrict__ g,
    float* __restrict__ ln)
{
  const int tid=threadIdx.x, wv=tid>>6, lane=tid&63;
  for (int b=wv; b<Bz; b+=4){
    float sum=0.f;
    for (int c=lane;c<Ez;c+=64) sum += h1[b*Ez+c];
#pragma unroll
    for (int off=32; off; off>>=1) sum += __shfl_xor(sum, off);
    const float mu = sum/(float)Ez;
    float s2=0.f;
    for (int c=lane;c<Ez;c+=64){ const float d=h1[b*Ez+c]-mu; s2=fmaf(d,d,s2); }
#pragma unroll
    for (int off=32; off; off>>=1) s2 += __shfl_xor(s2, off);
    const float inv = rsqrtf(s2/(float)Ez + LN_EPS);
    for (int c=lane;c<Ez;c+=64) ln[b*Ez+c] = (h1[b*Ez+c]-mu)*inv*g[c];
  }
}

// logits[b,v] = dot(ln[b,:], wte[v,:]) ; 64 rows per block, 16 rows per wave.
__global__ __launch_bounds__(256) void lm_head(
    const float* __restrict__ ln, const float* __restrict__ wte,
    float* __restrict__ out)
{
  __shared__ float sLn[Bz][EP];
  const int tid=threadIdx.x;
  for (int i4=tid; i4<Bz*Ez/4; i4+=256){
    const int b = i4/(Ez/4), c = (i4 - b*(Ez/4))<<2;
    *(float4*)(&sLn[b][c]) = *(const float4*)(ln + b*Ez + c);
  }
  __syncthreads();
  const int wv=tid>>6, lane=tid&63, rr=lane>>4, cl=lane&15;
  const int vbase = blockIdx.x*64 + wv*16 + rr;
  float acc[4][16];
#pragma unroll
  for (int k=0;k<4;k++)
#pragma unroll
    for (int b=0;b<16;b++) acc[k][b]=0.f;

  for (int j=0;j<12;j++){
    const int c = (cl<<2) + (j<<6);
    float4 w4[4];
#pragma unroll
    for (int k=0;k<4;k++){
      const int v = vbase + 4*k;
      if (v < Vz) w4[k] = *(const float4*)(wte + (size_t)v*Ez + c);
      else { w4[k].x=w4[k].y=w4[k].z=w4[k].w=0.f; }
    }
#pragma unroll
    for (int b=0;b<16;b++){
      const float4 hv = *(const float4*)(&sLn[b][c]);
#pragma unroll
      for (int k=0;k<4;k++) acc[k][b] = dot4acc(acc[k][b], w4[k], hv);
    }
  }
#pragma unroll
  for (int off=1; off<16; off<<=1)
#pragma unroll
    for (int k=0;k<4;k++)
#pragma unroll
      for (int b=0;b<16;b++) acc[k][b] += __shfl_xor(acc[k][b], off);

  if (cl==0){
#pragma unroll
    for (int k=0;k<4;k++){
      const int v = vbase + 4*k;
      if (v < Vz){
#pragma unroll
        for (int b=0;b<16;b++) out[(size_t)b*Vz + v] = acc[k][b];
      }
    }
  }
}

extern "C" void kernel_launch(void* const* d_in, const int* in_sizes, int n_in,
                              void* d_out, int out_size, void* d_ws, size_t ws_size,
                              hipStream_t stream) {
  const int*   idx = (const int*)  d_in[0];
  const float* wte = (const float*)d_in[1];
  const float* Wih = (const float*)d_in[2];
  const float* bih = (const float*)d_in[3];
  const float* Whh = (const float*)d_in[4];
  const float* bhh = (const float*)d_in[5];
  const float* g   = (const float*)d_in[6];
  float* out = (float*)d_out;

  unsigned* flags = (unsigned*)d_ws;            // words [0,256)
  unsigned* h0g   = (unsigned*)d_ws + 4096;     // 2 x 6144 words (fp16 pairs)
  unsigned* h1g   = h0g + 2*VECW;               // 2 x 6144 words
  float*    h1f   = (float*)(h1g + 2*VECW);     // B*E fp32 final h1
  float*    ln    = h1f + VEC;                  // B*E fp32

  (void)hipMemsetAsync(d_ws, 0, 16384, stream); // reset flags

  void* args[] = {(void*)&idx,(void*)&wte,(void*)&Wih,(void*)&bih,
                  (void*)&Whh,(void*)&bhh,(void*)&h0g,(void*)&h1g,
                  (void*)&h1f,(void*)&flags};
  (void)hipLaunchCooperativeKernel((void*)gru_scan, dim3(NBK), dim3(512), args, 0, stream);

  finalize_ln<<<1, 256, 0, stream>>>(h1f, g, ln);
  lm_head<<<786, 256, 0, stream>>>(ln, wte, out);
}

// Round 20
// 13978.857 us; speedup vs baseline: 1.6622x; 1.4645x over previous
//
#include <hip/hip_runtime.h>
#include <hip/hip_fp16.h>
#include <math.h>

#define Bz 16
#define Tz 1024
#define Ez 768
#define E3 2304
#define Vz 50257
#define NBK 256          // 256 blocks: 128 layer-0, 128 layer-1, 6 columns each
#define LN_EPS 1e-5f
#define VEC (Bz*Ez)      // 12288 floats per h vector
#define VECW 6144        // packed fp16: u32 words per h vector
#define EP 772           // padded LDS row stride

__device__ __forceinline__ float dot4acc(float acc, float4 w, float4 h){
  acc = fmaf(w.x,h.x,acc); acc = fmaf(w.y,h.y,acc);
  acc = fmaf(w.z,h.z,acc); acc = fmaf(w.w,h.w,acc);
  return acc;
}
__device__ __forceinline__ float sigm(float x){ return 1.0f/(1.0f+expf(-x)); }

__device__ __forceinline__ unsigned pack2(float a, float b){
  __half2 h = __floats2half2_rn(a, b);
  union{__half2 h2; unsigned u;} cv; cv.h2 = h; return cv.u;
}
__device__ __forceinline__ float2 unpack2(unsigned u){
  union{unsigned u; __half2 h2;} cv; cv.u = u;
  return __half22float2(cv.h2);
}

// ---- Staging envelope (empirical): scalar 32-bit relaxed-atomic loads with
// immediate LDS stores, <=4 outstanding per body. Byte-identical to R15. ----

__device__ __forceinline__ void stage_one_h(const unsigned* __restrict__ src,
                                            float (*dst)[EP], int tid){
#pragma unroll
  for (int k=0;k<3;k++){
    const int u0 = tid + (k<<9);
    const int u1 = u0 + 1536;
    const int u2 = u0 + 3072;
    const int u3 = u0 + 4608;
    const unsigned a0 = __hip_atomic_load(src+u0, __ATOMIC_RELAXED, __HIP_MEMORY_SCOPE_AGENT);
    const unsigned a1 = __hip_atomic_load(src+u1, __ATOMIC_RELAXED, __HIP_MEMORY_SCOPE_AGENT);
    const unsigned a2 = __hip_atomic_load(src+u2, __ATOMIC_RELAXED, __HIP_MEMORY_SCOPE_AGENT);
    const unsigned a3 = __hip_atomic_load(src+u3, __ATOMIC_RELAXED, __HIP_MEMORY_SCOPE_AGENT);
    {const int b=u0/384, c=(u0-b*384)<<1; const float2 f=unpack2(a0); dst[b][c]=f.x; dst[b][c+1]=f.y;}
    {const int b=u1/384, c=(u1-b*384)<<1; const float2 f=unpack2(a1); dst[b][c]=f.x; dst[b][c+1]=f.y;}
    {const int b=u2/384, c=(u2-b*384)<<1; const float2 f=unpack2(a2); dst[b][c]=f.x; dst[b][c+1]=f.y;}
    {const int b=u3/384, c=(u3-b*384)<<1; const float2 f=unpack2(a3); dst[b][c]=f.x; dst[b][c+1]=f.y;}
  }
}

__device__ __forceinline__ void zero_buf(float (*dst)[EP], int tid){
#pragma unroll
  for (int k=0;k<24;k++){
    const int u = tid + (k<<9);
    const int b = u/768, c = u - b*768;
    dst[b][c] = 0.f;
  }
}

// 3 rows/wave on waves 0-5: gOut[3*wv+r][batch] = wRow[r] . V[batch]
__device__ __forceinline__ void mm3(const float (*V)[EP],
                                    const float* const (&wRow)[3],
                                    float (*gOut)[17],
                                    int wv, int kq, int bb){
  float acc[3][4];
#pragma unroll
  for (int r=0;r<3;r++)
#pragma unroll
    for (int bi=0;bi<4;bi++) acc[r][bi]=0.f;
#pragma unroll 4
  for (int j=0;j<12;j++){
    const int kk = (j<<6) + (kq<<2);
    float4 w4[3];
#pragma unroll
    for (int r=0;r<3;r++) w4[r] = *(const float4*)(wRow[r] + kk);
#pragma unroll
    for (int bi=0;bi<4;bi++){
      const float4 hv = *(const float4*)&V[bb*4+bi][kk];
#pragma unroll
      for (int r=0;r<3;r++) acc[r][bi] = dot4acc(acc[r][bi], w4[r], hv);
    }
  }
#pragma unroll
  for (int r=0;r<3;r++)
#pragma unroll
    for (int bi=0;bi<4;bi++){
      float a = acc[r][bi];
      a += __shfl_xor(a,1); a += __shfl_xor(a,2);
      a += __shfl_xor(a,4); a += __shfl_xor(a,8);
      acc[r][bi]=a;
    }
  if (kq==0){
#pragma unroll
    for (int r=0;r<3;r++)
#pragma unroll
      for (int bi=0;bi<4;bi++) gOut[wv*3+r][bb*4+bi] = acc[r][bi];
  }
}

// ---------------------------------------------------------------------------
// Persistent cooperative scan, SOFTWARE-PIPELINED:
//  L0 at super-step s computes h0(s); L1 (lag-2) computes h1(s-2).
//  Post-barrier critical phase C: stage OWN-layer h -> gh matmul (18 rows,
//  6 waves) -> nonlin (uses gi precomputed last step) -> publish -> flag.
//  Overlap phase E (after flag, hidden under other blocks' barrier/stage):
//    L0: load x(s+1) (cached wte) + gi0 matmul for next step.
//    L1: stage h0(s-1) (2-barrier-old data) + gi1 matmul for next step.
//  h0 is TRIPLE-buffered (E reads race next step's publish); h1 double.
//  Barrier: R15 two-level + replicated go lines, verbatim.
// ---------------------------------------------------------------------------
__global__ __launch_bounds__(512) void gru_scan(
    const int* __restrict__ idx, const float* __restrict__ wte,
    const float* __restrict__ Wih, const float* __restrict__ bih,
    const float* __restrict__ Whh, const float* __restrict__ bhh,
    unsigned* __restrict__ h0g, unsigned* __restrict__ h1g,
    float* __restrict__ h1f,
    unsigned* __restrict__ flags, unsigned* __restrict__ go)
{
  __shared__ float bufX[Bz][EP];    // E-phase input (x or h0), consumed in E
  __shared__ float bufH[Bz][EP];    // C-phase own-layer h_prev
  __shared__ float gatesI[18][17];  // gi (precomputed in E, used next C)
  __shared__ float gatesG[18][17];  // gh (computed in C)
  __shared__ float biasS[36];
  __shared__ float hprev[Bz][6];    // own columns' h, exact fp32

  const int tid = threadIdx.x, bx = blockIdx.x;
  const int L = bx>>7, sub = bx&127, c0 = sub*6;
  const int wv = tid>>6, lane = tid&63, kq = lane&15, bb = lane>>4;

  const float* WihL = Wih + (size_t)L*E3*Ez;
  const float* WhhL = Whh + (size_t)L*E3*Ez;

  // waves 0-5: 3 rows each; row m=3*wv+r -> gate g=m/6, col cc=m%6
  const float* wiRow[3];
  const float* whRow[3];
#pragma unroll
  for (int r=0;r<3;r++){
    const int m = (wv<6 ? wv : 0)*3 + r, g = m/6, cc = m - g*6;
    wiRow[r] = WihL + (size_t)(g*Ez + c0 + cc)*Ez;
    whRow[r] = WhhL + (size_t)(g*Ez + c0 + cc)*Ez;
  }
  if (tid<36){
    const int mat = tid/18, mm = tid%18, g = mm/6, cc = mm-g*6;
    biasS[tid] = (mat ? bhh : bih)[L*E3 + g*Ez + c0 + cc];
  }
  if (tid<96) hprev[tid&15][tid>>4] = 0.f;

  // ---- prologue: L0 precomputes gi0 for x(0) ----
  if (L==0){
#pragma unroll
    for (int k4=0;k4<6;k4++){
      const int i4 = tid + (k4<<9);
      const int b = i4/192, c4 = i4 - b*192;
      const int row = idx[b*Tz];
      *(float4*)&bufX[b][c4<<2] = *(const float4*)(wte + (size_t)row*Ez + (c4<<2));
    }
    __syncthreads();
    if (wv<6) mm3(bufX, wiRow, gatesI, wv, kq, bb);
  }
  __syncthreads();

  for (int s=0; s<=Tz+1; ++s){
    // ---- grid wait (R15 two-level barrier, verbatim) ----
    if (s>0){
      const unsigned tgt = (unsigned)s;
      if (bx==0){
        if (tid<64){
          const unsigned* f = flags + (tid<<2);
          for(;;){
            const unsigned a0 = __hip_atomic_load(f+0, __ATOMIC_RELAXED, __HIP_MEMORY_SCOPE_AGENT);
            const unsigned a1 = __hip_atomic_load(f+1, __ATOMIC_RELAXED, __HIP_MEMORY_SCOPE_AGENT);
            const unsigned a2 = __hip_atomic_load(f+2, __ATOMIC_RELAXED, __HIP_MEMORY_SCOPE_AGENT);
            const unsigned a3 = __hip_atomic_load(f+3, __ATOMIC_RELAXED, __HIP_MEMORY_SCOPE_AGENT);
            const int ok = (a0>=tgt) & (a1>=tgt) & (a2>=tgt) & (a3>=tgt);
            if (__all(ok)) break;
            __builtin_amdgcn_s_sleep(1);
          }
          __hip_atomic_store(go + (tid<<5), tgt,
                             __ATOMIC_RELAXED, __HIP_MEMORY_SCOPE_AGENT);
        }
      } else {
        if (tid==0){
          const unsigned* gp = go + ((bx&63)<<5);
          while (__hip_atomic_load(gp, __ATOMIC_RELAXED, __HIP_MEMORY_SCOPE_AGENT) < tgt)
            __builtin_amdgcn_s_sleep(2);
        }
      }
      __syncthreads();
    }

    // ---- critical phase C ----
    const bool activeC = (L==0) ? (s<Tz) : (s>=2);
    if (activeC){
      if (L==0){
        if (s==0) zero_buf(bufH, tid);
        else      stage_one_h(h0g + (size_t)((s-1)%3)*VECW, bufH, tid);
      } else {
        if (s==2) zero_buf(bufH, tid);
        else      stage_one_h(h1g + (size_t)((s-1)&1)*VECW, bufH, tid);
      }
      __syncthreads();
      if (wv<6) mm3(bufH, whRow, gatesG, wv, kq, bb);
      __syncthreads();

      if (tid<48){
        const int b = tid&15, j = tid>>4;    // pair j: cols 2j, 2j+1
        float hv2[2];
#pragma unroll
        for (int e=0;e<2;e++){
          const int cc = 2*j+e;
          const float gir = gatesI[cc   ][b] + biasS[cc];
          const float giz = gatesI[6+cc ][b] + biasS[6+cc];
          const float gin = gatesI[12+cc][b] + biasS[12+cc];
          const float ghr = gatesG[cc   ][b] + biasS[18+cc];
          const float ghz = gatesG[6+cc ][b] + biasS[24+cc];
          const float ghn = gatesG[12+cc][b] + biasS[30+cc];
          const float r = sigm(gir+ghr);
          const float z = sigm(giz+ghz);
          const float n = tanhf(fmaf(r, ghn, gin));
          const float hp = hprev[b][cc];     // exact fp32 private state
          hv2[e] = fmaf(z, hp - n, n);
          hprev[b][cc] = hv2[e];
        }
        unsigned* hOutW = (L==0) ? (h0g + (size_t)(s%3)*VECW)
                                 : (h1g + (size_t)(s&1)*VECW);
        const unsigned pk = pack2(hv2[0], hv2[1]);
        __hip_atomic_store(hOutW + b*384 + sub*3 + j, pk,
                           __ATOMIC_RELAXED, __HIP_MEMORY_SCOPE_AGENT);
        if (L==1 && s==Tz+1){                // h1(Tz-1) -> fp32 for LN
          h1f[b*Ez + c0 + 2*j    ] = hv2[0];
          h1f[b*Ez + c0 + 2*j + 1] = hv2[1];
        }
      }
    }

    // ---- arrive: drain publish stores, then flag ----
    __syncthreads();
    if (tid==0)
      __hip_atomic_store(flags + bx, (unsigned)(s+1),
                         __ATOMIC_RELAXED, __HIP_MEMORY_SCOPE_AGENT);

    // ---- overlap phase E (hidden under other blocks' barrier/stage) ----
    const bool activeE = (L==0) ? (s < Tz-1) : (s>=1 && s<=Tz);
    if (activeE){
      if (L==0){
#pragma unroll
        for (int k4=0;k4<6;k4++){
          const int i4 = tid + (k4<<9);
          const int b = i4/192, c4 = i4 - b*192;
          const int row = idx[b*Tz + (s+1)];
          *(float4*)&bufX[b][c4<<2] = *(const float4*)(wte + (size_t)row*Ez + (c4<<2));
        }
      } else {
        // h0(s-1): published at step s-1, visible since barrier s (2-barrier-
        // old by consumption); h0 triple-buffered so next publish can't race.
        stage_one_h(h0g + (size_t)((s-1)%3)*VECW, bufX, tid);
      }
      __syncthreads();
      if (wv<6) mm3(bufX, wiRow, gatesI, wv, kq, bb);
    }
  }
}

// LayerNorm of final h1 (fp32) -> ln
__global__ __launch_bounds__(256) void finalize_ln(
    const float* __restrict__ h1, const float* __restrict__ g,
    float* __restrict__ ln)
{
  const int tid=threadIdx.x, wv=tid>>6, lane=tid&63;
  for (int b=wv; b<Bz; b+=4){
    float sum=0.f;
    for (int c=lane;c<Ez;c+=64) sum += h1[b*Ez+c];
#pragma unroll
    for (int off=32; off; off>>=1) sum += __shfl_xor(sum, off);
    const float mu = sum/(float)Ez;
    float s2=0.f;
    for (int c=lane;c<Ez;c+=64){ const float d=h1[b*Ez+c]-mu; s2=fmaf(d,d,s2); }
#pragma unroll
    for (int off=32; off; off>>=1) s2 += __shfl_xor(s2, off);
    const float inv = rsqrtf(s2/(float)Ez + LN_EPS);
    for (int c=lane;c<Ez;c+=64) ln[b*Ez+c] = (h1[b*Ez+c]-mu)*inv*g[c];
  }
}

// logits[b,v] = dot(ln[b,:], wte[v,:]) ; 64 rows per block, 16 rows per wave.
__global__ __launch_bounds__(256) void lm_head(
    const float* __restrict__ ln, const float* __restrict__ wte,
    float* __restrict__ out)
{
  __shared__ float sLn[Bz][EP];
  const int tid=threadIdx.x;
  for (int i4=tid; i4<Bz*Ez/4; i4+=256){
    const int b = i4/(Ez/4), c = (i4 - b*(Ez/4))<<2;
    *(float4*)(&sLn[b][c]) = *(const float4*)(ln + b*Ez + c);
  }
  __syncthreads();
  const int wv=tid>>6, lane=tid&63, rr=lane>>4, cl=lane&15;
  const int vbase = blockIdx.x*64 + wv*16 + rr;
  float acc[4][16];
#pragma unroll
  for (int k=0;k<4;k++)
#pragma unroll
    for (int b=0;b<16;b++) acc[k][b]=0.f;

  for (int j=0;j<12;j++){
    const int c = (cl<<2) + (j<<6);
    float4 w4[4];
#pragma unroll
    for (int k=0;k<4;k++){
      const int v = vbase + 4*k;
      if (v < Vz) w4[k] = *(const float4*)(wte + (size_t)v*Ez + c);
      else { w4[k].x=w4[k].y=w4[k].z=w4[k].w=0.f; }
    }
#pragma unroll
    for (int b=0;b<16;b++){
      const float4 hv = *(const float4*)(&sLn[b][c]);
#pragma unroll
      for (int k=0;k<4;k++) acc[k][b] = dot4acc(acc[k][b], w4[k], hv);
    }
  }
#pragma unroll
  for (int off=1; off<16; off<<=1)
#pragma unroll
    for (int k=0;k<4;k++)
#pragma unroll
      for (int b=0;b<16;b++) acc[k][b] += __shfl_xor(acc[k][b], off);

  if (cl==0){
#pragma unroll
    for (int k=0;k<4;k++){
      const int v = vbase + 4*k;
      if (v < Vz){
#pragma unroll
        for (int b=0;b<16;b++) out[(size_t)b*Vz + v] = acc[k][b];
      }
    }
  }
}

extern "C" void kernel_launch(void* const* d_in, const int* in_sizes, int n_in,
                              void* d_out, int out_size, void* d_ws, size_t ws_size,
                              hipStream_t stream) {
  const int*   idx = (const int*)  d_in[0];
  const float* wte = (const float*)d_in[1];
  const float* Wih = (const float*)d_in[2];
  const float* bih = (const float*)d_in[3];
  const float* Whh = (const float*)d_in[4];
  const float* bhh = (const float*)d_in[5];
  const float* g   = (const float*)d_in[6];
  float* out = (float*)d_out;

  unsigned* flags = (unsigned*)d_ws;            // words [0,256)
  unsigned* go    = (unsigned*)d_ws + 512;      // words [512,2560): 64 lines
  unsigned* h0g   = (unsigned*)d_ws + 4096;     // 3 x 6144 words (triple buf)
  unsigned* h1g   = h0g + 3*VECW;               // 2 x 6144 words
  float*    h1f   = (float*)(h1g + 2*VECW);     // B*E fp32 final h1
  float*    ln    = h1f + VEC;                  // B*E fp32

  (void)hipMemsetAsync(d_ws, 0, 16384, stream); // reset flags + go lines

  void* args[] = {(void*)&idx,(void*)&wte,(void*)&Wih,(void*)&bih,
                  (void*)&Whh,(void*)&bhh,(void*)&h0g,(void*)&h1g,
                  (void*)&h1f,(void*)&flags,(void*)&go};
  (void)hipLaunchCooperativeKernel((void*)gru_scan, dim3(NBK), dim3(512), args, 0, stream);

  finalize_ln<<<1, 256, 0, stream>>>(h1f, g, ln);
  lm_head<<<786, 256, 0, stream>>>(ln, wte, out);
}

// Round 21
// 12990.871 us; speedup vs baseline: 1.7886x; 1.0761x over previous
//
#include <hip/hip_runtime.h>
#include <hip/hip_fp16.h>
#include <math.h>

#define Bz 16
#define Tz 1024
#define Ez 768
#define E3 2304
#define Vz 50257
#define NBK 256          // 256 blocks: layer (2) x batch-group (2) x col-group (64)
#define LN_EPS 1e-5f
#define VEC (Bz*Ez)      // 12288 floats per full h vector
#define VECW 6144        // packed fp16: u32 words per full h vector
#define EP 772           // padded LDS row stride (fp32)
#define BS 8             // batches per block
#define CW 12            // columns per block

__device__ __forceinline__ float dot4acc(float acc, float4 w, float4 h){
  acc = fmaf(w.x,h.x,acc); acc = fmaf(w.y,h.y,acc);
  acc = fmaf(w.z,h.z,acc); acc = fmaf(w.w,h.w,acc);
  return acc;
}
__device__ __forceinline__ float sigm(float x){ return 1.0f/(1.0f+expf(-x)); }

__device__ __forceinline__ unsigned pack2(float a, float b){
  __half2 h = __floats2half2_rn(a, b);
  union{__half2 h2; unsigned u;} cv; cv.h2 = h; return cv.u;
}
__device__ __forceinline__ float2 unpack2(unsigned u){
  union{unsigned u; __half2 h2;} cv; cv.u = u;
  return __half22float2(cv.h2);
}

// ---- Staging envelope (empirical): scalar 32-bit relaxed-atomic loads with
// immediate LDS stores, <=4 outstanding per body. 2 bodies of 3 here. ----

// Stage this block's 8 batches of one h vector: 3072 words, 6/thread.
__device__ __forceinline__ void stage8(const unsigned* __restrict__ src,
                                       float (*dst)[EP], int tid){
#pragma unroll
  for (int k=0;k<2;k++){
    const int u0 = tid + k*1536;
    const int u1 = u0 + 512;
    const int u2 = u0 + 1024;
    const unsigned a0 = __hip_atomic_load(src+u0, __ATOMIC_RELAXED, __HIP_MEMORY_SCOPE_AGENT);
    const unsigned a1 = __hip_atomic_load(src+u1, __ATOMIC_RELAXED, __HIP_MEMORY_SCOPE_AGENT);
    const unsigned a2 = __hip_atomic_load(src+u2, __ATOMIC_RELAXED, __HIP_MEMORY_SCOPE_AGENT);
    {const int b=u0/384, c=(u0-b*384)<<1; const float2 f=unpack2(a0); dst[b][c]=f.x; dst[b][c+1]=f.y;}
    {const int b=u1/384, c=(u1-b*384)<<1; const float2 f=unpack2(a1); dst[b][c]=f.x; dst[b][c+1]=f.y;}
    {const int b=u2/384, c=(u2-b*384)<<1; const float2 f=unpack2(a2); dst[b][c]=f.x; dst[b][c+1]=f.y;}
  }
}

__device__ __forceinline__ void zero8(float (*dst)[EP], int tid){
#pragma unroll
  for (int k=0;k<6;k++){
    const int u = tid + (k<<9);
    const int b = u/384, c = (u-b*384)<<1;
    dst[b][c] = 0.f; dst[b][c+1] = 0.f;
  }
}

// 6 rows/wave on waves 0-5 (36 rows total), 8 batches (bb -> 2 each).
__device__ __forceinline__ void mm6(const float (*V)[EP],
                                    const float* const (&wRow)[6],
                                    float (*gOut)[9],
                                    int wv, int kq, int bb){
  float acc[6][2];
#pragma unroll
  for (int r=0;r<6;r++){ acc[r][0]=0.f; acc[r][1]=0.f; }
#pragma unroll 4
  for (int j=0;j<12;j++){
    const int kk = (j<<6) + (kq<<2);
    float4 w4[6];
#pragma unroll
    for (int r=0;r<6;r++) w4[r] = *(const float4*)(wRow[r] + kk);
#pragma unroll
    for (int bi=0;bi<2;bi++){
      const float4 hv = *(const float4*)&V[bb*2+bi][kk];
#pragma unroll
      for (int r=0;r<6;r++) acc[r][bi] = dot4acc(acc[r][bi], w4[r], hv);
    }
  }
#pragma unroll
  for (int r=0;r<6;r++)
#pragma unroll
    for (int bi=0;bi<2;bi++){
      float a = acc[r][bi];
      a += __shfl_xor(a,1); a += __shfl_xor(a,2);
      a += __shfl_xor(a,4); a += __shfl_xor(a,8);
      acc[r][bi]=a;
    }
  if (kq==0){
#pragma unroll
    for (int r=0;r<6;r++)
#pragma unroll
      for (int bi=0;bi<2;bi++) gOut[wv*6+r][bb*2+bi] = acc[r][bi];
  }
}

// ---------------------------------------------------------------------------
// Persistent cooperative scan, pipelined (R20) + 2D batch x column split:
// block = (L, bg, cg): layer L, batch group bg (8 batches), col group cg
// (12 cols). Staging reads only the block's 8-batch half of each h vector
// -> total UC transactions halve (1.18M/step), the R12-R20 binding resource.
// C phase: stage own-layer h -> gh matmul -> nonlin (gi from E) -> publish.
// E phase (post-flag): L0 loads x(s+1)+gi0; L1 stages h0(s-1)+gi1.
// h0 triple-buffered; h1 double. Barrier: R15 two-level relay verbatim.
// ---------------------------------------------------------------------------
__global__ __launch_bounds__(512) void gru_scan(
    const int* __restrict__ idx, const float* __restrict__ wte,
    const float* __restrict__ Wih, const float* __restrict__ bih,
    const float* __restrict__ Whh, const float* __restrict__ bhh,
    unsigned* __restrict__ h0g, unsigned* __restrict__ h1g,
    float* __restrict__ h1f,
    unsigned* __restrict__ flags, unsigned* __restrict__ go)
{
  __shared__ float bufX[BS][EP];    // E-phase input (x or h0)
  __shared__ float bufH[BS][EP];    // C-phase own-layer h_prev
  __shared__ float gatesI[36][9];   // gi (from E, used next C)
  __shared__ float gatesG[36][9];   // gh (computed in C)
  __shared__ float biasS[72];
  __shared__ float hprev[BS][CW];   // own (batch,col) h, exact fp32

  const int tid = threadIdx.x, bx = blockIdx.x;
  const int L = bx>>7, sub = bx&127;
  const int bg = sub>>6, cg = sub&63;
  const int c0 = cg*CW, b0 = bg*BS;
  const int wv = tid>>6, lane = tid&63, kq = lane&15, bb = lane>>4;

  const float* WihL = Wih + (size_t)L*E3*Ez;
  const float* WhhL = Whh + (size_t)L*E3*Ez;

  // waves 0-5: 6 rows each; row m -> gate g=m/12, col cc=m%12
  const float* wiRow[6];
  const float* whRow[6];
#pragma unroll
  for (int r=0;r<6;r++){
    const int m = (wv<6 ? wv : 0)*6 + r, g = m/12, cc = m - g*12;
    wiRow[r] = WihL + (size_t)(g*Ez + c0 + cc)*Ez;
    whRow[r] = WhhL + (size_t)(g*Ez + c0 + cc)*Ez;
  }
  if (tid<72){
    const int mat = tid/36, mm = tid%36, g = mm/12, cc = mm-g*12;
    biasS[tid] = (mat ? bhh : bih)[L*E3 + g*Ez + c0 + cc];
  }
  if (tid<96) hprev[tid&7][tid>>3] = 0.f;

  // ---- prologue: L0 precomputes gi0 for x(0) ----
  if (L==0){
#pragma unroll
    for (int k=0;k<3;k++){
      const int i4 = tid + (k<<9);
      const int b = i4/192, c4 = i4 - b*192;
      const int row = idx[(b0+b)*Tz];
      *(float4*)&bufX[b][c4<<2] = *(const float4*)(wte + (size_t)row*Ez + (c4<<2));
    }
    __syncthreads();
    if (wv<6) mm6(bufX, wiRow, gatesI, wv, kq, bb);
  }
  __syncthreads();

  for (int s=0; s<=Tz+1; ++s){
    // ---- grid wait (two-level relay + replicated go lines) ----
    if (s>0){
      const unsigned tgt = (unsigned)s;
      if (bx==0){
        if (tid<64){
          const unsigned* f = flags + (tid<<2);
          for(;;){
            const unsigned a0 = __hip_atomic_load(f+0, __ATOMIC_RELAXED, __HIP_MEMORY_SCOPE_AGENT);
            const unsigned a1 = __hip_atomic_load(f+1, __ATOMIC_RELAXED, __HIP_MEMORY_SCOPE_AGENT);
            const unsigned a2 = __hip_atomic_load(f+2, __ATOMIC_RELAXED, __HIP_MEMORY_SCOPE_AGENT);
            const unsigned a3 = __hip_atomic_load(f+3, __ATOMIC_RELAXED, __HIP_MEMORY_SCOPE_AGENT);
            const int ok = (a0>=tgt) & (a1>=tgt) & (a2>=tgt) & (a3>=tgt);
            if (__all(ok)) break;
            __builtin_amdgcn_s_sleep(1);
          }
          __hip_atomic_store(go + (tid<<5), tgt,
                             __ATOMIC_RELAXED, __HIP_MEMORY_SCOPE_AGENT);
        }
      } else {
        if (tid==0){
          const unsigned* gp = go + ((bx&63)<<5);
          while (__hip_atomic_load(gp, __ATOMIC_RELAXED, __HIP_MEMORY_SCOPE_AGENT) < tgt)
            __builtin_amdgcn_s_sleep(2);
        }
      }
      __syncthreads();
    }

    // ---- critical phase C ----
    const bool activeC = (L==0) ? (s<Tz) : (s>=2);
    if (activeC){
      if (L==0){
        if (s==0) zero8(bufH, tid);
        else      stage8(h0g + (size_t)((s-1)%3)*VECW + bg*3072, bufH, tid);
      } else {
        if (s==2) zero8(bufH, tid);
        else      stage8(h1g + (size_t)((s-1)&1)*VECW + bg*3072, bufH, tid);
      }
      __syncthreads();
      if (wv<6) mm6(bufH, whRow, gatesG, wv, kq, bb);
      __syncthreads();

      if (tid<48){
        const int b = tid&7, j = tid>>3;     // pair j: cols 2j, 2j+1 (j<6)
        float hv2[2];
#pragma unroll
        for (int e=0;e<2;e++){
          const int cc = 2*j+e;
          const float gir = gatesI[cc    ][b] + biasS[cc];
          const float giz = gatesI[12+cc][b] + biasS[12+cc];
          const float gin = gatesI[24+cc][b] + biasS[24+cc];
          const float ghr = gatesG[cc    ][b] + biasS[36+cc];
          const float ghz = gatesG[12+cc][b] + biasS[48+cc];
          const float ghn = gatesG[24+cc][b] + biasS[60+cc];
          const float r = sigm(gir+ghr);
          const float z = sigm(giz+ghz);
          const float n = tanhf(fmaf(r, ghn, gin));
          const float hp = hprev[b][cc];     // exact fp32 private state
          hv2[e] = fmaf(z, hp - n, n);
          hprev[b][cc] = hv2[e];
        }
        unsigned* hOutW = (L==0) ? (h0g + (size_t)(s%3)*VECW)
                                 : (h1g + (size_t)(s&1)*VECW);
        const unsigned pk = pack2(hv2[0], hv2[1]);
        __hip_atomic_store(hOutW + (b0+b)*384 + cg*6 + j, pk,
                           __ATOMIC_RELAXED, __HIP_MEMORY_SCOPE_AGENT);
        if (L==1 && s==Tz+1){                // h1(Tz-1) -> fp32 for LN
          h1f[(b0+b)*Ez + c0 + 2*j    ] = hv2[0];
          h1f[(b0+b)*Ez + c0 + 2*j + 1] = hv2[1];
        }
      }
    }

    // ---- arrive: drain publish stores, then flag ----
    __syncthreads();
    if (tid==0)
      __hip_atomic_store(flags + bx, (unsigned)(s+1),
                         __ATOMIC_RELAXED, __HIP_MEMORY_SCOPE_AGENT);

    // ---- overlap phase E ----
    const bool activeE = (L==0) ? (s < Tz-1) : (s>=1 && s<=Tz);
    if (activeE){
      if (L==0){
#pragma unroll
        for (int k=0;k<3;k++){
          const int i4 = tid + (k<<9);
          const int b = i4/192, c4 = i4 - b*192;
          const int row = idx[(b0+b)*Tz + (s+1)];
          *(float4*)&bufX[b][c4<<2] = *(const float4*)(wte + (size_t)row*Ez + (c4<<2));
        }
      } else {
        // h0(s-1): 2-barrier-old by consumption; h0 triple-buffered.
        stage8(h0g + (size_t)((s-1)%3)*VECW + bg*3072, bufX, tid);
      }
      __syncthreads();
      if (wv<6) mm6(bufX, wiRow, gatesI, wv, kq, bb);
    }
  }
}

// LayerNorm of final h1 (fp32) -> ln
__global__ __launch_bounds__(256) void finalize_ln(
    const float* __restrict__ h1, const float* __restrict__ g,
    float* __restrict__ ln)
{
  const int tid=threadIdx.x, wv=tid>>6, lane=tid&63;
  for (int b=wv; b<Bz; b+=4){
    float sum=0.f;
    for (int c=lane;c<Ez;c+=64) sum += h1[b*Ez+c];
#pragma unroll
    for (int off=32; off; off>>=1) sum += __shfl_xor(sum, off);
    const float mu = sum/(float)Ez;
    float s2=0.f;
    for (int c=lane;c<Ez;c+=64){ const float d=h1[b*Ez+c]-mu; s2=fmaf(d,d,s2); }
#pragma unroll
    for (int off=32; off; off>>=1) s2 += __shfl_xor(s2, off);
    const float inv = rsqrtf(s2/(float)Ez + LN_EPS);
    for (int c=lane;c<Ez;c+=64) ln[b*Ez+c] = (h1[b*Ez+c]-mu)*inv*g[c];
  }
}

// logits[b,v] = dot(ln[b,:], wte[v,:]) ; 64 rows per block, 16 rows per wave.
__global__ __launch_bounds__(256) void lm_head(
    const float* __restrict__ ln, const float* __restrict__ wte,
    float* __restrict__ out)
{
  __shared__ float sLn[Bz][EP];
  const int tid=threadIdx.x;
  for (int i4=tid; i4<Bz*Ez/4; i4+=256){
    const int b = i4/(Ez/4), c = (i4 - b*(Ez/4))<<2;
    *(float4*)(&sLn[b][c]) = *(const float4*)(ln + b*Ez + c);
  }
  __syncthreads();
  const int wv=tid>>6, lane=tid&63, rr=lane>>4, cl=lane&15;
  const int vbase = blockIdx.x*64 + wv*16 + rr;
  float acc[4][16];
#pragma unroll
  for (int k=0;k<4;k++)
#pragma unroll
    for (int b=0;b<16;b++) acc[k][b]=0.f;

  for (int j=0;j<12;j++){
    const int c = (cl<<2) + (j<<6);
    float4 w4[4];
#pragma unroll
    for (int k=0;k<4;k++){
      const int v = vbase + 4*k;
      if (v < Vz) w4[k] = *(const float4*)(wte + (size_t)v*Ez + c);
      else { w4[k].x=w4[k].y=w4[k].z=w4[k].w=0.f; }
    }
#pragma unroll
    for (int b=0;b<16;b++){
      const float4 hv = *(const float4*)(&sLn[b][c]);
#pragma unroll
      for (int k=0;k<4;k++) acc[k][b] = dot4acc(acc[k][b], w4[k], hv);
    }
  }
#pragma unroll
  for (int off=1; off<16; off<<=1)
#pragma unroll
    for (int k=0;k<4;k++)
#pragma unroll
      for (int b=0;b<16;b++) acc[k][b] += __shfl_xor(acc[k][b], off);

  if (cl==0){
#pragma unroll
    for (int k=0;k<4;k++){
      const int v = vbase + 4*k;
      if (v < Vz){
#pragma unroll
        for (int b=0;b<16;b++) out[(size_t)b*Vz + v] = acc[k][b];
      }
    }
  }
}

extern "C" void kernel_launch(void* const* d_in, const int* in_sizes, int n_in,
                              void* d_out, int out_size, void* d_ws, size_t ws_size,
                              hipStream_t stream) {
  const int*   idx = (const int*)  d_in[0];
  const float* wte = (const float*)d_in[1];
  const float* Wih = (const float*)d_in[2];
  const float* bih = (const float*)d_in[3];
  const float* Whh = (const float*)d_in[4];
  const float* bhh = (const float*)d_in[5];
  const float* g   = (const float*)d_in[6];
  float* out = (float*)d_out;

  unsigned* flags = (unsigned*)d_ws;            // words [0,256)
  unsigned* go    = (unsigned*)d_ws + 512;      // words [512,2560): 64 lines
  unsigned* h0g   = (unsigned*)d_ws + 4096;     // 3 x 6144 words (triple buf)
  unsigned* h1g   = h0g + 3*VECW;               // 2 x 6144 words
  float*    h1f   = (float*)(h1g + 2*VECW);     // B*E fp32 final h1
  float*    ln    = h1f + VEC;                  // B*E fp32

  (void)hipMemsetAsync(d_ws, 0, 16384, stream); // reset flags + go lines

  void* args[] = {(void*)&idx,(void*)&wte,(void*)&Wih,(void*)&bih,
                  (void*)&Whh,(void*)&bhh,(void*)&h0g,(void*)&h1g,
                  (void*)&h1f,(void*)&flags,(void*)&go};
  (void)hipLaunchCooperativeKernel((void*)gru_scan, dim3(NBK), dim3(512), args, 0, stream);

  finalize_ln<<<1, 256, 0, stream>>>(h1f, g, ln);
  lm_head<<<786, 256, 0, stream>>>(ln, wte, out);
}